// Round 1
// baseline (427.386 us; speedup 1.0000x reference)
//
#include <hip/hip_runtime.h>
#include <math.h>

#define D 128

typedef __attribute__((ext_vector_type(8))) short short8_t;
typedef __attribute__((ext_vector_type(4))) float f32x4;

__device__ __forceinline__ short f2bf(float f) {
  union { float f; unsigned u; } v; v.f = f;
  unsigned r = v.u + 0x7FFFu + ((v.u >> 16) & 1u);  // round-to-nearest-even
  return (short)(r >> 16);
}

// ---------------------------------------------------------------------------
// prep: Wc = W0 @ W0 (f32) -> bf16 ; convert W2, Wl -> bf16
// blocks 0..63: Wc ; 64..127: W2 ; 128..191: Wl
// ---------------------------------------------------------------------------
__global__ void prep_kernel(const float* __restrict__ W0, const float* __restrict__ W2,
                            const float* __restrict__ Wl,
                            short* __restrict__ Wcb, short* __restrict__ W2b,
                            short* __restrict__ Wlb) {
  int b = blockIdx.x, t = threadIdx.x;
  if (b < 64) {
    int idx = b * 256 + t;
    int r = idx >> 7, c = idx & 127;
    float s = 0.f;
    for (int k = 0; k < D; ++k) s += W0[r * D + k] * W0[k * D + c];
    Wcb[idx] = f2bf(s);
  } else if (b < 128) {
    int idx = (b - 64) * 256 + t;
    W2b[idx] = f2bf(W2[idx]);
  } else {
    int idx = (b - 128) * 256 + t;
    Wlb[idx] = f2bf(Wl[idx]);
  }
}

// ---------------------------------------------------------------------------
// h = x  (residual init; edge kernel atomically accumulates on top)
// ---------------------------------------------------------------------------
__global__ void copy_kernel(const float* __restrict__ x, float* __restrict__ h, long n4) {
  long i = (long)blockIdx.x * blockDim.x + threadIdx.x;
  long stride = (long)gridDim.x * blockDim.x;
  for (; i < n4; i += stride) ((f32x4*)h)[i] = ((const f32x4*)x)[i];
}

// ---------------------------------------------------------------------------
// Wxh = x @ Wl^T + bl   (bf16 MFMA, 64 rows/block, 4 waves x 16 rows)
// ---------------------------------------------------------------------------
__global__ __launch_bounds__(256, 2) void node_gemm_kernel(
    const float* __restrict__ x, const short* __restrict__ Wlb,
    const float* __restrict__ bl, float* __restrict__ Wxh, int N) {
  __shared__ short Wl_s[D * D];
  const int tid = threadIdx.x;
  const int lane = tid & 63, wave = tid >> 6;
  const int q = lane & 15, g = lane >> 4;

  // stage Wl (bf16, XOR-swizzled rows)
  for (int it = 0; it < 8; ++it) {
    int eoff = (it * 256 + tid) * 8;
    int row = eoff >> 7, col = eoff & 127;
    int scol = col ^ ((row & 7) << 3);
    *(short8_t*)&Wl_s[row * D + scol] = *(const short8_t*)&Wlb[eoff];
  }

  const int rbase = blockIdx.x * 64 + wave * 16;
  int arow = rbase + q; if (arow > N - 1) arow = N - 1;
  short8_t a[4];
  const float* src = x + (size_t)arow * D;
#pragma unroll
  for (int c = 0; c < 4; ++c) {
    int kb = c * 32 + g * 8;
    f32x4 v0 = *(const f32x4*)(src + kb);
    f32x4 v1 = *(const f32x4*)(src + kb + 4);
    short8_t t;
    t[0]=f2bf(v0.x); t[1]=f2bf(v0.y); t[2]=f2bf(v0.z); t[3]=f2bf(v0.w);
    t[4]=f2bf(v1.x); t[5]=f2bf(v1.y); t[6]=f2bf(v1.z); t[7]=f2bf(v1.w);
    a[c] = t;
  }

  __syncthreads();

  f32x4 acc[8];
#pragma unroll
  for (int n = 0; n < 8; ++n) acc[n] = f32x4{0.f, 0.f, 0.f, 0.f};
#pragma unroll
  for (int n = 0; n < 8; ++n) {
    int row = n * 16 + q;
    int sw = (row & 7) << 3;
#pragma unroll
    for (int c = 0; c < 4; ++c) {
      int col = (c * 32 + g * 8) ^ sw;
      short8_t b = *(const short8_t*)&Wl_s[row * D + col];
      acc[n] = __builtin_amdgcn_mfma_f32_16x16x32_bf16(a[c], b, acc[n], 0, 0, 0);
    }
  }

#pragma unroll
  for (int n = 0; n < 8; ++n) {
    int col = n * 16 + q;
    float bias = bl[col];
#pragma unroll
    for (int r = 0; r < 4; ++r) {
      int orow = rbase + g * 4 + r;
      if (orow < N) Wxh[(size_t)orow * D + col] = acc[n][r] + bias;
    }
  }
}

// ---------------------------------------------------------------------------
// edge kernel: u = rbf@Wc^T + b0 ; m = silu(u) @ W2^T + b2 ;
//              atomicAdd(h[i], m * Wxh[j])
// 64 edges/block, 4 waves x 16 edges. LDS: Wc(32K) + W2(32K) + m tiles(16K)
// ---------------------------------------------------------------------------
__global__ __launch_bounds__(256, 2) void edge_kernel(
    const float* __restrict__ rbf, const int* __restrict__ gi, const int* __restrict__ gj,
    const float* __restrict__ b0v, const float* __restrict__ b2v,
    const float* __restrict__ Wxh, const short* __restrict__ Wcb,
    const short* __restrict__ W2b, float* __restrict__ h, int E) {
  __shared__ short Wc_s[D * D];
  __shared__ short W2_s[D * D];
  __shared__ short m_s[4][16 * D];

  const int tid = threadIdx.x;
  const int lane = tid & 63, wave = tid >> 6;
  const int q = lane & 15, g = lane >> 4;

  // stage both weight matrices (bf16, XOR-swizzled)
  for (int it = 0; it < 8; ++it) {
    int eoff = (it * 256 + tid) * 8;
    int row = eoff >> 7, col = eoff & 127;
    int scol = col ^ ((row & 7) << 3);
    *(short8_t*)&Wc_s[row * D + scol] = *(const short8_t*)&Wcb[eoff];
    *(short8_t*)&W2_s[row * D + scol] = *(const short8_t*)&W2b[eoff];
  }

  const long ebase = (long)blockIdx.x * 64 + wave * 16;

  // A fragments: 16 rbf rows, bf16
  long arow = ebase + q; if (arow > E - 1) arow = E - 1;
  short8_t a[4];
  {
    const float* src = rbf + arow * D;
#pragma unroll
    for (int c = 0; c < 4; ++c) {
      int kb = c * 32 + g * 8;
      f32x4 v0 = *(const f32x4*)(src + kb);
      f32x4 v1 = *(const f32x4*)(src + kb + 4);
      short8_t t;
      t[0]=f2bf(v0.x); t[1]=f2bf(v0.y); t[2]=f2bf(v0.z); t[3]=f2bf(v0.w);
      t[4]=f2bf(v1.x); t[5]=f2bf(v1.y); t[6]=f2bf(v1.z); t[7]=f2bf(v1.w);
      a[c] = t;
    }
  }

  // destination/source indices for this lane's 4 output rows
  int jr[4], ir[4], valid[4];
#pragma unroll
  for (int r = 0; r < 4; ++r) {
    long e = ebase + g * 4 + r;
    valid[r] = (e < E);
    long ec = valid[r] ? e : (E - 1);
    jr[r] = gj[ec];
    ir[r] = gi[ec];
  }

  __syncthreads();

  // GEMM1: u = rbf @ Wc^T
  f32x4 acc[8];
#pragma unroll
  for (int n = 0; n < 8; ++n) acc[n] = f32x4{0.f, 0.f, 0.f, 0.f};
#pragma unroll
  for (int n = 0; n < 8; ++n) {
    int row = n * 16 + q;
    int sw = (row & 7) << 3;
#pragma unroll
    for (int c = 0; c < 4; ++c) {
      int col = (c * 32 + g * 8) ^ sw;
      short8_t b = *(const short8_t*)&Wc_s[row * D + col];
      acc[n] = __builtin_amdgcn_mfma_f32_16x16x32_bf16(a[c], b, acc[n], 0, 0, 0);
    }
  }

  // silu(u + b0) -> per-wave LDS m tile (bf16, swizzled) for layout transpose
  short* ms = &m_s[wave][0];
#pragma unroll
  for (int n = 0; n < 8; ++n) {
    int col = n * 16 + q;
    float bias = b0v[col];
#pragma unroll
    for (int r = 0; r < 4; ++r) {
      int row = g * 4 + r;
      float u = acc[n][r] + bias;
      float s = u / (1.0f + __expf(-u));
      ms[row * D + (col ^ ((row & 7) << 3))] = f2bf(s);
    }
  }

  // re-read as A fragments (same-wave LDS round trip; compiler inserts lgkmcnt)
  short8_t a2[4];
  {
    int row = q;
    int sw = (row & 7) << 3;
#pragma unroll
    for (int c = 0; c < 4; ++c) {
      int col = (c * 32 + g * 8) ^ sw;
      a2[c] = *(const short8_t*)&ms[row * D + col];
    }
  }

  // GEMM2: m = silu(u) @ W2^T
  f32x4 acc2[8];
#pragma unroll
  for (int n = 0; n < 8; ++n) acc2[n] = f32x4{0.f, 0.f, 0.f, 0.f};
#pragma unroll
  for (int n = 0; n < 8; ++n) {
    int row = n * 16 + q;
    int sw = (row & 7) << 3;
#pragma unroll
    for (int c = 0; c < 4; ++c) {
      int col = (c * 32 + g * 8) ^ sw;
      short8_t b = *(const short8_t*)&W2_s[row * D + col];
      acc2[n] = __builtin_amdgcn_mfma_f32_16x16x32_bf16(a2[c], b, acc2[n], 0, 0, 0);
    }
  }

  // epilogue: msg = (m + b2) * Wxh[j] ; scatter-add into h[i]
#pragma unroll
  for (int n = 0; n < 8; ++n) {
    int col = n * 16 + q;
    float bias = b2v[col];
#pragma unroll
    for (int r = 0; r < 4; ++r) {
      if (valid[r]) {
        float val = (acc2[n][r] + bias) * Wxh[(size_t)jr[r] * D + col];
        __hip_atomic_fetch_add(&h[(size_t)ir[r] * D + col], val,
                               __ATOMIC_RELAXED, __HIP_MEMORY_SCOPE_AGENT);
      }
    }
  }
}

// ---------------------------------------------------------------------------
// LayerNorm: out = (h - mu)/sqrt(var+1e-5) * gamma + beta ; one wave per row
// ---------------------------------------------------------------------------
__global__ __launch_bounds__(256) void ln_kernel(const float* __restrict__ h,
                                                 const float* __restrict__ gamma,
                                                 const float* __restrict__ beta,
                                                 float* __restrict__ out, int N) {
  int wave = threadIdx.x >> 6, lane = threadIdx.x & 63;
  long row = (long)blockIdx.x * 4 + wave;
  if (row >= N) return;
  const float* hr = h + row * D;
  int c = lane * 2;
  float v0 = hr[c], v1 = hr[c + 1];
  float sum = v0 + v1;
  float sq = v0 * v0 + v1 * v1;
#pragma unroll
  for (int o = 32; o; o >>= 1) {
    sum += __shfl_xor(sum, o, 64);
    sq += __shfl_xor(sq, o, 64);
  }
  float mu = sum * (1.0f / 128.0f);
  float var = sq * (1.0f / 128.0f) - mu * mu;
  float rstd = rsqrtf(var + 1e-5f);
  float o0 = (v0 - mu) * rstd * gamma[c] + beta[c];
  float o1 = (v1 - mu) * rstd * gamma[c + 1] + beta[c + 1];
  out[row * D + c] = o0;
  out[row * D + c + 1] = o1;
}

// ---------------------------------------------------------------------------
extern "C" void kernel_launch(void* const* d_in, const int* in_sizes, int n_in,
                              void* d_out, int out_size, void* d_ws, size_t ws_size,
                              hipStream_t stream) {
  const float* x    = (const float*)d_in[0];
  const int*   gi   = (const int*)d_in[1];
  const int*   gj   = (const int*)d_in[2];
  const float* rbf  = (const float*)d_in[3];
  const float* Wl   = (const float*)d_in[4];
  const float* bl   = (const float*)d_in[5];
  const float* W0   = (const float*)d_in[6];
  const float* b0   = (const float*)d_in[7];
  const float* W2   = (const float*)d_in[8];
  const float* b2   = (const float*)d_in[9];
  const float* gam  = (const float*)d_in[10];
  const float* bet  = (const float*)d_in[11];

  const int N = in_sizes[0] / D;  // 50000
  const int E = in_sizes[1];      // 600000

  char* ws = (char*)d_ws;
  float* h   = (float*)ws;                               // N*D f32
  float* Wxh = (float*)(ws + (size_t)N * D * 4);         // N*D f32
  short* Wcb = (short*)(ws + (size_t)N * D * 8);         // 128x128 bf16
  short* W2b = Wcb + D * D;
  short* Wlb = W2b + D * D;

  prep_kernel<<<192, 256, 0, stream>>>(W0, W2, Wl, Wcb, W2b, Wlb);
  copy_kernel<<<2048, 256, 0, stream>>>(x, h, (long)N * D / 4);
  node_gemm_kernel<<<(N + 63) / 64, 256, 0, stream>>>(x, Wlb, bl, Wxh, N);
  edge_kernel<<<(E + 63) / 64, 256, 0, stream>>>(rbf, gi, gj, b0, b2, Wxh, Wcb, W2b, h, E);
  ln_kernel<<<(N + 3) / 4, 256, 0, stream>>>(h, gam, bet, (float*)d_out, N);
}

// Round 2
// 370.855 us; speedup vs baseline: 1.1524x; 1.1524x over previous
//
#include <hip/hip_runtime.h>
#include <math.h>

#define D 128

typedef __attribute__((ext_vector_type(8))) short short8_t;
typedef __attribute__((ext_vector_type(4))) float f32x4;
typedef __attribute__((ext_vector_type(2))) float f32x2;

__device__ __forceinline__ short f2bf(float f) {
  union { float f; unsigned u; } v; v.f = f;
  unsigned r = v.u + 0x7FFFu + ((v.u >> 16) & 1u);  // round-to-nearest-even
  return (short)(r >> 16);
}
__device__ __forceinline__ float bf2f(unsigned u16) {
  union { unsigned u; float f; } v; v.u = u16 << 16; return v.f;
}

// ---------------------------------------------------------------------------
// prep: Wc = W0@W0 -> bf16 ; W2,Wl -> bf16 ; zero count[]
// blocks 0..63: Wc ; 64..127: W2 ; 128..191: Wl ; 192..: zero count
// ---------------------------------------------------------------------------
__global__ void prep_kernel(const float* __restrict__ W0, const float* __restrict__ W2,
                            const float* __restrict__ Wl,
                            short* __restrict__ Wcb, short* __restrict__ W2b,
                            short* __restrict__ Wlb, int* __restrict__ count, int N) {
  int b = blockIdx.x, t = threadIdx.x;
  if (b < 64) {
    int idx = b * 256 + t;
    int r = idx >> 7, c = idx & 127;
    float s = 0.f;
    for (int k = 0; k < D; ++k) s += W0[r * D + k] * W0[k * D + c];
    Wcb[idx] = f2bf(s);
  } else if (b < 128) {
    int idx = (b - 64) * 256 + t;
    W2b[idx] = f2bf(W2[idx]);
  } else if (b < 192) {
    int idx = (b - 128) * 256 + t;
    Wlb[idx] = f2bf(Wl[idx]);
  } else {
    int idx = (b - 192) * 256 + t;
    if (idx < N) count[idx] = 0;
  }
}

// ---------------------------------------------------------------------------
// histogram of destination indices
// ---------------------------------------------------------------------------
__global__ void hist_kernel(const int* __restrict__ gi, int* __restrict__ count, int E) {
  int e = blockIdx.x * 256 + threadIdx.x;
  if (e < E) atomicAdd(&count[gi[e]], 1);
}

// ---------------------------------------------------------------------------
// exclusive scan of count -> start[0..N], woff (single block, 1024 threads)
// ---------------------------------------------------------------------------
__global__ __launch_bounds__(1024) void scan_kernel(const int* __restrict__ count,
                                                    int* __restrict__ start,
                                                    int* __restrict__ woff, int N) {
  __shared__ int wsum[16];
  const int tid = threadIdx.x, lane = tid & 63, wave = tid >> 6;
  const int chunk = (N + 1023) / 1024;
  int lo = tid * chunk, hi = lo + chunk; if (hi > N) hi = N; if (lo > N) lo = N;
  int s = 0;
  for (int i = lo; i < hi; ++i) s += count[i];
  int v = s;
#pragma unroll
  for (int o = 1; o < 64; o <<= 1) {
    int u = __shfl_up(v, o, 64);
    if (lane >= o) v += u;
  }
  if (lane == 63) wsum[wave] = v;
  __syncthreads();
  if (wave == 0 && lane < 16) {
    int w = wsum[lane];
#pragma unroll
    for (int o = 1; o < 16; o <<= 1) {
      int u = __shfl_up(w, o, 64);
      if (lane >= o) w += u;
    }
    wsum[lane] = w;
  }
  __syncthreads();
  int base = (wave ? wsum[wave - 1] : 0) + (v - s);  // exclusive prefix of this chunk
  for (int i = lo; i < hi; ++i) {
    start[i] = base; woff[i] = base; base += count[i];
  }
  if (tid == 1023) start[N] = base;  // == E
}

// ---------------------------------------------------------------------------
// scatter: perm[pos] = e ; jperm[pos] = j[e]   (CSR by destination i)
// ---------------------------------------------------------------------------
__global__ void scatter_kernel(const int* __restrict__ gi, const int* __restrict__ gj,
                               int* __restrict__ woff, int* __restrict__ perm,
                               int* __restrict__ jperm, int E) {
  int e = blockIdx.x * 256 + threadIdx.x;
  if (e < E) {
    int pos = atomicAdd(&woff[gi[e]], 1);
    perm[pos] = e;
    jperm[pos] = gj[e];
  }
}

// ---------------------------------------------------------------------------
// Wxh = x @ Wl^T + bl   (bf16 MFMA, 64 rows/block)
// ---------------------------------------------------------------------------
__global__ __launch_bounds__(256, 2) void node_gemm_kernel(
    const float* __restrict__ x, const short* __restrict__ Wlb,
    const float* __restrict__ bl, float* __restrict__ Wxh, int N) {
  __shared__ short Wl_s[D * D];
  const int tid = threadIdx.x;
  const int lane = tid & 63, wave = tid >> 6;
  const int q = lane & 15, g = lane >> 4;

  for (int it = 0; it < 8; ++it) {
    int eoff = (it * 256 + tid) * 8;
    int row = eoff >> 7, col = eoff & 127;
    int scol = col ^ ((row & 7) << 3);
    *(short8_t*)&Wl_s[row * D + scol] = *(const short8_t*)&Wlb[eoff];
  }

  const int rbase = blockIdx.x * 64 + wave * 16;
  int arow = rbase + q; if (arow > N - 1) arow = N - 1;
  short8_t a[4];
  const float* src = x + (size_t)arow * D;
#pragma unroll
  for (int c = 0; c < 4; ++c) {
    int kb = c * 32 + g * 8;
    f32x4 v0 = *(const f32x4*)(src + kb);
    f32x4 v1 = *(const f32x4*)(src + kb + 4);
    short8_t t;
    t[0]=f2bf(v0.x); t[1]=f2bf(v0.y); t[2]=f2bf(v0.z); t[3]=f2bf(v0.w);
    t[4]=f2bf(v1.x); t[5]=f2bf(v1.y); t[6]=f2bf(v1.z); t[7]=f2bf(v1.w);
    a[c] = t;
  }

  __syncthreads();

  f32x4 acc[8];
#pragma unroll
  for (int n = 0; n < 8; ++n) acc[n] = f32x4{0.f, 0.f, 0.f, 0.f};
#pragma unroll
  for (int n = 0; n < 8; ++n) {
    int row = n * 16 + q;
    int sw = (row & 7) << 3;
#pragma unroll
    for (int c = 0; c < 4; ++c) {
      int col = (c * 32 + g * 8) ^ sw;
      short8_t b = *(const short8_t*)&Wl_s[row * D + col];
      acc[n] = __builtin_amdgcn_mfma_f32_16x16x32_bf16(a[c], b, acc[n], 0, 0, 0);
    }
  }

#pragma unroll
  for (int n = 0; n < 8; ++n) {
    int col = n * 16 + q;
    float bias = bl[col];
#pragma unroll
    for (int r = 0; r < 4; ++r) {
      int orow = rbase + g * 4 + r;
      if (orow < N) Wxh[(size_t)orow * D + col] = acc[n][r] + bias;
    }
  }
}

// ---------------------------------------------------------------------------
// filter kernel (persistent): m = (silu(rbf@Wc^T + b0)) @ W2^T + b2 -> bf16 rows
// 64 edges/tile, 4 waves x 16 edges. No indices, no atomics — pure streaming.
// ---------------------------------------------------------------------------
__global__ __launch_bounds__(256, 2) void filter_kernel(
    const float* __restrict__ rbf, const float* __restrict__ b0v,
    const float* __restrict__ b2v, const short* __restrict__ Wcb,
    const short* __restrict__ W2b, short* __restrict__ mbuf, int E, int ntiles) {
  __shared__ short Wc_s[D * D];
  __shared__ short W2_s[D * D];
  __shared__ short m_s[4][16 * D];

  const int tid = threadIdx.x;
  const int lane = tid & 63, wave = tid >> 6;
  const int q = lane & 15, g = lane >> 4;

  for (int it = 0; it < 8; ++it) {
    int eoff = (it * 256 + tid) * 8;
    int row = eoff >> 7, col = eoff & 127;
    int scol = col ^ ((row & 7) << 3);
    *(short8_t*)&Wc_s[row * D + scol] = *(const short8_t*)&Wcb[eoff];
    *(short8_t*)&W2_s[row * D + scol] = *(const short8_t*)&W2b[eoff];
  }

  // hoist biases (col = n*16+q per lane)
  float b0r[8], b2r[8];
#pragma unroll
  for (int n = 0; n < 8; ++n) { b0r[n] = b0v[n * 16 + q]; b2r[n] = b2v[n * 16 + q]; }

  __syncthreads();

  short* ms = &m_s[wave][0];

  for (int tile = blockIdx.x; tile < ntiles; tile += gridDim.x) {
    const long ebase = (long)tile * 64 + wave * 16;

    long arow = ebase + q; if (arow > E - 1) arow = E - 1;
    short8_t a[4];
    {
      const float* src = rbf + arow * D;
#pragma unroll
      for (int c = 0; c < 4; ++c) {
        int kb = c * 32 + g * 8;
        f32x4 v0 = *(const f32x4*)(src + kb);
        f32x4 v1 = *(const f32x4*)(src + kb + 4);
        short8_t t;
        t[0]=f2bf(v0.x); t[1]=f2bf(v0.y); t[2]=f2bf(v0.z); t[3]=f2bf(v0.w);
        t[4]=f2bf(v1.x); t[5]=f2bf(v1.y); t[6]=f2bf(v1.z); t[7]=f2bf(v1.w);
        a[c] = t;
      }
    }

    // GEMM1: u = rbf @ Wc^T
    f32x4 acc[8];
#pragma unroll
    for (int n = 0; n < 8; ++n) acc[n] = f32x4{0.f, 0.f, 0.f, 0.f};
#pragma unroll
    for (int n = 0; n < 8; ++n) {
      int row = n * 16 + q;
      int sw = (row & 7) << 3;
#pragma unroll
      for (int c = 0; c < 4; ++c) {
        int col = (c * 32 + g * 8) ^ sw;
        short8_t b = *(const short8_t*)&Wc_s[row * D + col];
        acc[n] = __builtin_amdgcn_mfma_f32_16x16x32_bf16(a[c], b, acc[n], 0, 0, 0);
      }
    }

    // silu(u + b0) -> wave-private LDS tile (bf16, swizzled) for transpose
#pragma unroll
    for (int n = 0; n < 8; ++n) {
      int col = n * 16 + q;
#pragma unroll
      for (int r = 0; r < 4; ++r) {
        int row = g * 4 + r;
        float u = acc[n][r] + b0r[n];
        float s = u / (1.0f + __expf(-u));
        ms[row * D + (col ^ ((row & 7) << 3))] = f2bf(s);
      }
    }

    short8_t a2[4];
    {
      int sw = (q & 7) << 3;
#pragma unroll
      for (int c = 0; c < 4; ++c) {
        int col = (c * 32 + g * 8) ^ sw;
        a2[c] = *(const short8_t*)&ms[q * D + col];
      }
    }

    // GEMM2: m = silu(u) @ W2^T
    f32x4 acc2[8];
#pragma unroll
    for (int n = 0; n < 8; ++n) acc2[n] = f32x4{0.f, 0.f, 0.f, 0.f};
#pragma unroll
    for (int n = 0; n < 8; ++n) {
      int row = n * 16 + q;
      int sw = (row & 7) << 3;
#pragma unroll
      for (int c = 0; c < 4; ++c) {
        int col = (c * 32 + g * 8) ^ sw;
        short8_t b = *(const short8_t*)&W2_s[row * D + col];
        acc2[n] = __builtin_amdgcn_mfma_f32_16x16x32_bf16(a2[c], b, acc2[n], 0, 0, 0);
      }
    }

    // m + b2 -> bf16 -> LDS (swizzled) -> coalesced global rows
#pragma unroll
    for (int n = 0; n < 8; ++n) {
      int col = n * 16 + q;
#pragma unroll
      for (int r = 0; r < 4; ++r) {
        int row = g * 4 + r;
        ms[row * D + (col ^ ((row & 7) << 3))] = f2bf(acc2[n][r] + b2r[n]);
      }
    }
#pragma unroll
    for (int it = 0; it < 4; ++it) {
      int idx = it * 64 + lane;
      int row = idx >> 4, c8 = idx & 15;
      long er = ebase + row;
      short8_t v = *(const short8_t*)&ms[row * D + ((c8 ^ (row & 7)) << 3)];
      if (er < E) *(short8_t*)&mbuf[er * D + c8 * 8] = v;
    }
  }
}

// ---------------------------------------------------------------------------
// gather + residual + LayerNorm: one wave per node
// agg = sum_{e in E(i)} m[e] * Wxh[j[e]] ; out = LN(x + agg)*gamma + beta
// ---------------------------------------------------------------------------
__global__ __launch_bounds__(256) void gather_ln_kernel(
    const short* __restrict__ mbuf, const float* __restrict__ Wxh,
    const int* __restrict__ perm, const int* __restrict__ jperm,
    const int* __restrict__ start, const float* __restrict__ x,
    const float* __restrict__ gamma, const float* __restrict__ beta,
    float* __restrict__ out, int N) {
  const int wave = threadIdx.x >> 6, lane = threadIdx.x & 63;
  const int node = blockIdx.x * 4 + wave;
  if (node >= N) return;
  const int s = start[node], e = start[node + 1];

  float a0 = 0.f, a1 = 0.f;
  for (int base = s; base < e; base += 64) {
    int k = base + lane;
    int pe = 0, pj = 0;
    if (k < e) { pe = perm[k]; pj = jperm[k]; }
    int cnt = e - base; if (cnt > 64) cnt = 64;
    int t = 0;
    for (; t + 2 <= cnt; t += 2) {
      int e0 = __shfl(pe, t, 64),     j0 = __shfl(pj, t, 64);
      int e1 = __shfl(pe, t + 1, 64), j1 = __shfl(pj, t + 1, 64);
      unsigned mm0 = *(const unsigned*)&mbuf[(size_t)e0 * D + lane * 2];
      f32x2 w0 = *(const f32x2*)&Wxh[(size_t)j0 * D + lane * 2];
      unsigned mm1 = *(const unsigned*)&mbuf[(size_t)e1 * D + lane * 2];
      f32x2 w1 = *(const f32x2*)&Wxh[(size_t)j1 * D + lane * 2];
      a0 += bf2f(mm0 & 0xffffu) * w0.x; a1 += bf2f(mm0 >> 16) * w0.y;
      a0 += bf2f(mm1 & 0xffffu) * w1.x; a1 += bf2f(mm1 >> 16) * w1.y;
    }
    for (; t < cnt; ++t) {
      int e0 = __shfl(pe, t, 64), j0 = __shfl(pj, t, 64);
      unsigned mm0 = *(const unsigned*)&mbuf[(size_t)e0 * D + lane * 2];
      f32x2 w0 = *(const f32x2*)&Wxh[(size_t)j0 * D + lane * 2];
      a0 += bf2f(mm0 & 0xffffu) * w0.x; a1 += bf2f(mm0 >> 16) * w0.y;
    }
  }

  f32x2 xv = *(const f32x2*)&x[(size_t)node * D + lane * 2];
  float h0 = xv.x + a0, h1 = xv.y + a1;
  float sum = h0 + h1, sq = h0 * h0 + h1 * h1;
#pragma unroll
  for (int o = 32; o; o >>= 1) {
    sum += __shfl_xor(sum, o, 64);
    sq += __shfl_xor(sq, o, 64);
  }
  float mu = sum * (1.0f / 128.0f);
  float var = sq * (1.0f / 128.0f) - mu * mu;
  float rstd = rsqrtf(var + 1e-5f);
  int c = lane * 2;
  f32x2 gv = *(const f32x2*)&gamma[c];
  f32x2 bv = *(const f32x2*)&beta[c];
  f32x2 ov;
  ov.x = (h0 - mu) * rstd * gv.x + bv.x;
  ov.y = (h1 - mu) * rstd * gv.y + bv.y;
  *(f32x2*)&out[(size_t)node * D + c] = ov;
}

// ---------------------------------------------------------------------------
extern "C" void kernel_launch(void* const* d_in, const int* in_sizes, int n_in,
                              void* d_out, int out_size, void* d_ws, size_t ws_size,
                              hipStream_t stream) {
  const float* x    = (const float*)d_in[0];
  const int*   gi   = (const int*)d_in[1];
  const int*   gj   = (const int*)d_in[2];
  const float* rbf  = (const float*)d_in[3];
  const float* Wl   = (const float*)d_in[4];
  const float* bl   = (const float*)d_in[5];
  const float* W0   = (const float*)d_in[6];
  const float* b0   = (const float*)d_in[7];
  const float* W2   = (const float*)d_in[8];
  const float* b2   = (const float*)d_in[9];
  const float* gam  = (const float*)d_in[10];
  const float* bet  = (const float*)d_in[11];

  const int N = in_sizes[0] / D;  // 50000
  const int E = in_sizes[1];      // 600000

  char* ws = (char*)d_ws;
  size_t off = 0;
  float* Wxh  = (float*)(ws + off); off += (size_t)N * D * 4;
  short* mbuf = (short*)(ws + off); off += (size_t)E * D * 2;
  int*   cnt  = (int*)(ws + off);   off += (size_t)N * 4;
  int*   strt = (int*)(ws + off);   off += (size_t)(N + 1) * 4;
  int*   woff = (int*)(ws + off);   off += (size_t)N * 4;
  int*   perm = (int*)(ws + off);   off += (size_t)E * 4;
  int*   jprm = (int*)(ws + off);   off += (size_t)E * 4;
  short* Wcb  = (short*)(ws + off); off += D * D * 2;
  short* W2b  = (short*)(ws + off); off += D * D * 2;
  short* Wlb  = (short*)(ws + off); off += D * D * 2;

  const int ntiles = (E + 63) / 64;
  const int egrid = (E + 255) / 256;

  prep_kernel<<<192 + (N + 255) / 256, 256, 0, stream>>>(W0, W2, Wl, Wcb, W2b, Wlb, cnt, N);
  hist_kernel<<<egrid, 256, 0, stream>>>(gi, cnt, E);
  scan_kernel<<<1, 1024, 0, stream>>>(cnt, strt, woff, N);
  scatter_kernel<<<egrid, 256, 0, stream>>>(gi, gj, woff, perm, jprm, E);
  node_gemm_kernel<<<(N + 63) / 64, 256, 0, stream>>>(x, Wlb, bl, Wxh, N);
  filter_kernel<<<512, 256, 0, stream>>>(rbf, b0, b2, Wcb, W2b, mbuf, E, ntiles);
  gather_ln_kernel<<<(N + 3) / 4, 256, 0, stream>>>(mbuf, Wxh, perm, jprm, strt, x, gam, bet, (float*)d_out, N);
}

// Round 3
// 368.069 us; speedup vs baseline: 1.1612x; 1.0076x over previous
//
#include <hip/hip_runtime.h>
#include <math.h>

#define D 128

typedef __attribute__((ext_vector_type(8))) short short8_t;
typedef __attribute__((ext_vector_type(4))) float f32x4;
typedef __attribute__((ext_vector_type(2))) float f32x2;

__device__ __forceinline__ short f2bf(float f) {
  union { float f; unsigned u; } v; v.f = f;
  unsigned r = v.u + 0x7FFFu + ((v.u >> 16) & 1u);  // round-to-nearest-even
  return (short)(r >> 16);
}
__device__ __forceinline__ float bf2f(unsigned u16) {
  union { unsigned u; float f; } v; v.u = u16 << 16; return v.f;
}

// ---------------------------------------------------------------------------
// prep: Wc = W0@W0 -> bf16 ; W2,Wl -> bf16 ; zero count[]
// ---------------------------------------------------------------------------
__global__ void prep_kernel(const float* __restrict__ W0, const float* __restrict__ W2,
                            const float* __restrict__ Wl,
                            short* __restrict__ Wcb, short* __restrict__ W2b,
                            short* __restrict__ Wlb, int* __restrict__ count, int N) {
  int b = blockIdx.x, t = threadIdx.x;
  if (b < 64) {
    int idx = b * 256 + t;
    int r = idx >> 7, c = idx & 127;
    float s = 0.f;
    for (int k = 0; k < D; ++k) s += W0[r * D + k] * W0[k * D + c];
    Wcb[idx] = f2bf(s);
  } else if (b < 128) {
    int idx = (b - 64) * 256 + t;
    W2b[idx] = f2bf(W2[idx]);
  } else if (b < 192) {
    int idx = (b - 128) * 256 + t;
    Wlb[idx] = f2bf(Wl[idx]);
  } else {
    int idx = (b - 192) * 256 + t;
    if (idx < N) count[idx] = 0;
  }
}

// ---------------------------------------------------------------------------
__global__ void hist_kernel(const int* __restrict__ gi, int* __restrict__ count, int E) {
  int e = blockIdx.x * 256 + threadIdx.x;
  if (e < E) atomicAdd(&count[gi[e]], 1);
}

// ---------------------------------------------------------------------------
// exclusive scan of count -> start[0..N], woff (single block, 1024 threads)
// ---------------------------------------------------------------------------
__global__ __launch_bounds__(1024) void scan_kernel(const int* __restrict__ count,
                                                    int* __restrict__ start,
                                                    int* __restrict__ woff, int N) {
  __shared__ int wsum[16];
  const int tid = threadIdx.x, lane = tid & 63, wave = tid >> 6;
  const int chunk = (N + 1023) / 1024;
  int lo = tid * chunk, hi = lo + chunk; if (hi > N) hi = N; if (lo > N) lo = N;
  int s = 0;
  for (int i = lo; i < hi; ++i) s += count[i];
  int v = s;
#pragma unroll
  for (int o = 1; o < 64; o <<= 1) {
    int u = __shfl_up(v, o, 64);
    if (lane >= o) v += u;
  }
  if (lane == 63) wsum[wave] = v;
  __syncthreads();
  if (wave == 0 && lane < 16) {
    int w = wsum[lane];
#pragma unroll
    for (int o = 1; o < 16; o <<= 1) {
      int u = __shfl_up(w, o, 64);
      if (lane >= o) w += u;
    }
    wsum[lane] = w;
  }
  __syncthreads();
  int base = (wave ? wsum[wave - 1] : 0) + (v - s);
  for (int i = lo; i < hi; ++i) {
    start[i] = base; woff[i] = base; base += count[i];
  }
  if (tid == 1023) start[N] = base;
}

// ---------------------------------------------------------------------------
// scatter: CSR by destination. perm[pos]=e, jperm[pos]=j[e], iperm[pos]=i[e]
// ---------------------------------------------------------------------------
__global__ void scatter_kernel(const int* __restrict__ gi, const int* __restrict__ gj,
                               int* __restrict__ woff, int* __restrict__ perm,
                               int* __restrict__ jperm, int* __restrict__ iperm, int E) {
  int e = blockIdx.x * 256 + threadIdx.x;
  if (e < E) {
    int i = gi[e];
    int pos = atomicAdd(&woff[i], 1);
    perm[pos] = e;
    jperm[pos] = gj[e];
    iperm[pos] = i;
  }
}

// ---------------------------------------------------------------------------
// h = x  (residual init; fused kernel atomically accumulates on top)
// ---------------------------------------------------------------------------
__global__ void copy_kernel(const float* __restrict__ x, float* __restrict__ h, long n4) {
  long i = (long)blockIdx.x * blockDim.x + threadIdx.x;
  long stride = (long)gridDim.x * blockDim.x;
  for (; i < n4; i += stride) ((f32x4*)h)[i] = ((const f32x4*)x)[i];
}

// ---------------------------------------------------------------------------
// Wxh = x @ Wl^T + bl -> bf16   (bf16 MFMA, 64 rows/block)
// ---------------------------------------------------------------------------
__global__ __launch_bounds__(256, 2) void node_gemm_kernel(
    const float* __restrict__ x, const short* __restrict__ Wlb,
    const float* __restrict__ bl, short* __restrict__ WxhB, int N) {
  __shared__ short Wl_s[D * D];
  const int tid = threadIdx.x;
  const int lane = tid & 63, wave = tid >> 6;
  const int q = lane & 15, g = lane >> 4;

  for (int it = 0; it < 8; ++it) {
    int eoff = (it * 256 + tid) * 8;
    int row = eoff >> 7, col = eoff & 127;
    int scol = col ^ ((row & 7) << 3);
    *(short8_t*)&Wl_s[row * D + scol] = *(const short8_t*)&Wlb[eoff];
  }

  const int rbase = blockIdx.x * 64 + wave * 16;
  int arow = rbase + q; if (arow > N - 1) arow = N - 1;
  short8_t a[4];
  const float* src = x + (size_t)arow * D;
#pragma unroll
  for (int c = 0; c < 4; ++c) {
    int kb = c * 32 + g * 8;
    f32x4 v0 = *(const f32x4*)(src + kb);
    f32x4 v1 = *(const f32x4*)(src + kb + 4);
    short8_t t;
    t[0]=f2bf(v0.x); t[1]=f2bf(v0.y); t[2]=f2bf(v0.z); t[3]=f2bf(v0.w);
    t[4]=f2bf(v1.x); t[5]=f2bf(v1.y); t[6]=f2bf(v1.z); t[7]=f2bf(v1.w);
    a[c] = t;
  }

  __syncthreads();

  f32x4 acc[8];
#pragma unroll
  for (int n = 0; n < 8; ++n) acc[n] = f32x4{0.f, 0.f, 0.f, 0.f};
#pragma unroll
  for (int n = 0; n < 8; ++n) {
    int row = n * 16 + q;
    int sw = (row & 7) << 3;
#pragma unroll
    for (int c = 0; c < 4; ++c) {
      int col = (c * 32 + g * 8) ^ sw;
      short8_t b = *(const short8_t*)&Wl_s[row * D + col];
      acc[n] = __builtin_amdgcn_mfma_f32_16x16x32_bf16(a[c], b, acc[n], 0, 0, 0);
    }
  }

#pragma unroll
  for (int n = 0; n < 8; ++n) {
    int col = n * 16 + q;
    float bias = bl[col];
#pragma unroll
    for (int r = 0; r < 4; ++r) {
      int orow = rbase + g * 4 + r;
      if (orow < N) WxhB[(size_t)orow * D + col] = f2bf(acc[n][r] + bias);
    }
  }
}

// ---------------------------------------------------------------------------
// fused edge kernel (persistent, CSR edge order):
//   m = (silu(rbf[perm[e]]@Wc^T + b0)) @ W2^T + b2     (MFMA, LDS transpose)
//   segmented reduce over destination runs: h[i] += sum m ⊙ Wxh[j]
// 64 edges/tile, 4 waves x 16 edges. LDS: Wc 32K + W2 32K + m tiles 16K = 80K
// ---------------------------------------------------------------------------
__global__ __launch_bounds__(256, 2) void fused_edge_kernel(
    const float* __restrict__ rbf, const float* __restrict__ b0v,
    const float* __restrict__ b2v, const short* __restrict__ Wcb,
    const short* __restrict__ W2b, const short* __restrict__ WxhB,
    const int* __restrict__ perm, const int* __restrict__ jperm,
    const int* __restrict__ iperm, float* __restrict__ h, int E, int ntiles) {
  __shared__ short Wc_s[D * D];
  __shared__ short W2_s[D * D];
  __shared__ short m_s[4][16 * D];

  const int tid = threadIdx.x;
  const int lane = tid & 63, wave = tid >> 6;
  const int q = lane & 15, g = lane >> 4;

  for (int it = 0; it < 8; ++it) {
    int eoff = (it * 256 + tid) * 8;
    int row = eoff >> 7, col = eoff & 127;
    int scol = col ^ ((row & 7) << 3);
    *(short8_t*)&Wc_s[row * D + scol] = *(const short8_t*)&Wcb[eoff];
    *(short8_t*)&W2_s[row * D + scol] = *(const short8_t*)&W2b[eoff];
  }

  float b0r[8], b2r[8];
#pragma unroll
  for (int n = 0; n < 8; ++n) { b0r[n] = b0v[n * 16 + q]; b2r[n] = b2v[n * 16 + q]; }

  __syncthreads();

  short* ms = &m_s[wave][0];

  for (int tile = blockIdx.x; tile < ntiles; tile += gridDim.x) {
    const int eb = tile * 64 + wave * 16;

    // per-lane edge indices for this wave's 16 edges (lane q)
    int eq = eb + q; if (eq > E - 1) eq = E - 1;
    const int pe = perm[eq];
    const int pj = jperm[eq];
    const int pi = iperm[eq];

    // broadcast j/i for all 16 rows; prefetch Wxh[j] row fragment (bf16 x2)
    unsigned wv[16]; int iv[16];
#pragma unroll
    for (int r = 0; r < 16; ++r) {
      int jr = __shfl(pj, r, 64);
      iv[r] = __shfl(pi, r, 64);
      wv[r] = *(const unsigned*)&WxhB[(size_t)jr * D + lane * 2];
    }

    // A fragments from gathered rbf rows
    short8_t a[4];
    {
      const float* src = rbf + (size_t)pe * D;
#pragma unroll
      for (int c = 0; c < 4; ++c) {
        int kb = c * 32 + g * 8;
        f32x4 v0 = *(const f32x4*)(src + kb);
        f32x4 v1 = *(const f32x4*)(src + kb + 4);
        short8_t t;
        t[0]=f2bf(v0.x); t[1]=f2bf(v0.y); t[2]=f2bf(v0.z); t[3]=f2bf(v0.w);
        t[4]=f2bf(v1.x); t[5]=f2bf(v1.y); t[6]=f2bf(v1.z); t[7]=f2bf(v1.w);
        a[c] = t;
      }
    }

    // GEMM1: u = rbf @ Wc^T
    f32x4 acc[8];
#pragma unroll
    for (int n = 0; n < 8; ++n) acc[n] = f32x4{0.f, 0.f, 0.f, 0.f};
#pragma unroll
    for (int n = 0; n < 8; ++n) {
      int row = n * 16 + q;
      int sw = (row & 7) << 3;
#pragma unroll
      for (int c = 0; c < 4; ++c) {
        int col = (c * 32 + g * 8) ^ sw;
        short8_t b = *(const short8_t*)&Wc_s[row * D + col];
        acc[n] = __builtin_amdgcn_mfma_f32_16x16x32_bf16(a[c], b, acc[n], 0, 0, 0);
      }
    }

    // silu(u + b0) -> wave-private LDS tile (bf16, swizzled) for transpose
#pragma unroll
    for (int n = 0; n < 8; ++n) {
      int col = n * 16 + q;
#pragma unroll
      for (int r = 0; r < 4; ++r) {
        int row = g * 4 + r;
        float u = acc[n][r] + b0r[n];
        float s = u / (1.0f + __expf(-u));
        ms[row * D + (col ^ ((row & 7) << 3))] = f2bf(s);
      }
    }

    short8_t a2[4];
    {
      int sw = (q & 7) << 3;
#pragma unroll
      for (int c = 0; c < 4; ++c) {
        int col = (c * 32 + g * 8) ^ sw;
        a2[c] = *(const short8_t*)&ms[q * D + col];
      }
    }

    // GEMM2: m = silu(u) @ W2^T
    f32x4 acc2[8];
#pragma unroll
    for (int n = 0; n < 8; ++n) acc2[n] = f32x4{0.f, 0.f, 0.f, 0.f};
#pragma unroll
    for (int n = 0; n < 8; ++n) {
      int row = n * 16 + q;
      int sw = (row & 7) << 3;
#pragma unroll
      for (int c = 0; c < 4; ++c) {
        int col = (c * 32 + g * 8) ^ sw;
        short8_t b = *(const short8_t*)&W2_s[row * D + col];
        acc2[n] = __builtin_amdgcn_mfma_f32_16x16x32_bf16(a2[c], b, acc2[n], 0, 0, 0);
      }
    }

    // m + b2 -> bf16 back into the wave tile
#pragma unroll
    for (int n = 0; n < 8; ++n) {
      int col = n * 16 + q;
#pragma unroll
      for (int r = 0; r < 4; ++r) {
        int row = g * 4 + r;
        ms[row * D + (col ^ ((row & 7) << 3))] = f2bf(acc2[n][r] + b2r[n]);
      }
    }

    // segmented reduce: lane owns cols {2*lane, 2*lane+1}; rows sorted by i
    int nv = E - eb; if (nv > 16) nv = 16;
    float a0 = 0.f, a1 = 0.f;
    int cur = -1;
#pragma unroll
    for (int r = 0; r < 16; ++r) {
      if (r < nv) {
        if (iv[r] != cur) {
          if (cur >= 0) {
            float* dst = &h[(size_t)cur * D + lane * 2];
            __hip_atomic_fetch_add(dst, a0, __ATOMIC_RELAXED, __HIP_MEMORY_SCOPE_AGENT);
            __hip_atomic_fetch_add(dst + 1, a1, __ATOMIC_RELAXED, __HIP_MEMORY_SCOPE_AGENT);
            a0 = a1 = 0.f;
          }
          cur = iv[r];
        }
        unsigned mv = *(const unsigned*)&ms[r * D + ((lane * 2) ^ ((r & 7) << 3))];
        a0 += bf2f(mv & 0xffffu) * bf2f(wv[r] & 0xffffu);
        a1 += bf2f(mv >> 16) * bf2f(wv[r] >> 16);
      }
    }
    if (cur >= 0) {
      float* dst = &h[(size_t)cur * D + lane * 2];
      __hip_atomic_fetch_add(dst, a0, __ATOMIC_RELAXED, __HIP_MEMORY_SCOPE_AGENT);
      __hip_atomic_fetch_add(dst + 1, a1, __ATOMIC_RELAXED, __HIP_MEMORY_SCOPE_AGENT);
    }
  }
}

// ---------------------------------------------------------------------------
// LayerNorm: out = (h - mu)/sqrt(var+1e-5) * gamma + beta ; one wave per row
// ---------------------------------------------------------------------------
__global__ __launch_bounds__(256) void ln_kernel(const float* __restrict__ h,
                                                 const float* __restrict__ gamma,
                                                 const float* __restrict__ beta,
                                                 float* __restrict__ out, int N) {
  int wave = threadIdx.x >> 6, lane = threadIdx.x & 63;
  long row = (long)blockIdx.x * 4 + wave;
  if (row >= N) return;
  const float* hr = h + row * D;
  int c = lane * 2;
  f32x2 v = *(const f32x2*)&hr[c];
  float sum = v.x + v.y;
  float sq = v.x * v.x + v.y * v.y;
#pragma unroll
  for (int o = 32; o; o >>= 1) {
    sum += __shfl_xor(sum, o, 64);
    sq += __shfl_xor(sq, o, 64);
  }
  float mu = sum * (1.0f / 128.0f);
  float var = sq * (1.0f / 128.0f) - mu * mu;
  float rstd = rsqrtf(var + 1e-5f);
  f32x2 gv = *(const f32x2*)&gamma[c];
  f32x2 bv = *(const f32x2*)&beta[c];
  f32x2 ov;
  ov.x = (v.x - mu) * rstd * gv.x + bv.x;
  ov.y = (v.y - mu) * rstd * gv.y + bv.y;
  *(f32x2*)&out[row * D + c] = ov;
}

// ---------------------------------------------------------------------------
extern "C" void kernel_launch(void* const* d_in, const int* in_sizes, int n_in,
                              void* d_out, int out_size, void* d_ws, size_t ws_size,
                              hipStream_t stream) {
  const float* x    = (const float*)d_in[0];
  const int*   gi   = (const int*)d_in[1];
  const int*   gj   = (const int*)d_in[2];
  const float* rbf  = (const float*)d_in[3];
  const float* Wl   = (const float*)d_in[4];
  const float* bl   = (const float*)d_in[5];
  const float* W0   = (const float*)d_in[6];
  const float* b0   = (const float*)d_in[7];
  const float* W2   = (const float*)d_in[8];
  const float* b2   = (const float*)d_in[9];
  const float* gam  = (const float*)d_in[10];
  const float* bet  = (const float*)d_in[11];

  const int N = in_sizes[0] / D;  // 50000
  const int E = in_sizes[1];      // 600000

  char* ws = (char*)d_ws;
  size_t off = 0;
  float* h    = (float*)(ws + off); off += (size_t)N * D * 4;
  short* WxhB = (short*)(ws + off); off += (size_t)N * D * 2;
  int*   cnt  = (int*)(ws + off);   off += (size_t)N * 4;
  int*   strt = (int*)(ws + off);   off += (size_t)(N + 1) * 4;
  int*   woff = (int*)(ws + off);   off += (size_t)N * 4;
  int*   perm = (int*)(ws + off);   off += (size_t)E * 4;
  int*   jprm = (int*)(ws + off);   off += (size_t)E * 4;
  int*   iprm = (int*)(ws + off);   off += (size_t)E * 4;
  short* Wcb  = (short*)(ws + off); off += D * D * 2;
  short* W2b  = (short*)(ws + off); off += D * D * 2;
  short* Wlb  = (short*)(ws + off); off += D * D * 2;

  const int ntiles = (E + 63) / 64;
  const int egrid = (E + 255) / 256;

  prep_kernel<<<192 + (N + 255) / 256, 256, 0, stream>>>(W0, W2, Wl, Wcb, W2b, Wlb, cnt, N);
  hist_kernel<<<egrid, 256, 0, stream>>>(gi, cnt, E);
  scan_kernel<<<1, 1024, 0, stream>>>(cnt, strt, woff, N);
  scatter_kernel<<<egrid, 256, 0, stream>>>(gi, gj, woff, perm, jprm, iprm, E);
  copy_kernel<<<2048, 256, 0, stream>>>(x, h, (long)N * D / 4);
  node_gemm_kernel<<<(N + 63) / 64, 256, 0, stream>>>(x, Wlb, bl, WxhB, N);
  fused_edge_kernel<<<512, 256, 0, stream>>>(rbf, b0, b2, Wcb, W2b, WxhB,
                                             perm, jprm, iprm, h, E, ntiles);
  ln_kernel<<<(N + 3) / 4, 256, 0, stream>>>(h, gam, bet, (float*)d_out, N);
}

// Round 4
// 353.583 us; speedup vs baseline: 1.2087x; 1.0410x over previous
//
#include <hip/hip_runtime.h>
#include <math.h>

#define D 128

typedef __attribute__((ext_vector_type(8))) short short8_t;
typedef __attribute__((ext_vector_type(4))) float f32x4;
typedef __attribute__((ext_vector_type(2))) float f32x2;

__device__ __forceinline__ short f2bf(float f) {
  union { float f; unsigned u; } v; v.f = f;
  unsigned r = v.u + 0x7FFFu + ((v.u >> 16) & 1u);  // round-to-nearest-even
  return (short)(r >> 16);
}
__device__ __forceinline__ float bf2f(unsigned u16) {
  union { unsigned u; float f; } v; v.u = u16 << 16; return v.f;
}

// ---------------------------------------------------------------------------
// prep: Wc = W0@W0 -> bf16 ; W2,Wl -> bf16 ; zero count[]
// ---------------------------------------------------------------------------
__global__ void prep_kernel(const float* __restrict__ W0, const float* __restrict__ W2,
                            const float* __restrict__ Wl,
                            short* __restrict__ Wcb, short* __restrict__ W2b,
                            short* __restrict__ Wlb, int* __restrict__ count, int N) {
  int b = blockIdx.x, t = threadIdx.x;
  if (b < 64) {
    int idx = b * 256 + t;
    int r = idx >> 7, c = idx & 127;
    float s = 0.f;
    for (int k = 0; k < D; ++k) s += W0[r * D + k] * W0[k * D + c];
    Wcb[idx] = f2bf(s);
  } else if (b < 128) {
    int idx = (b - 64) * 256 + t;
    W2b[idx] = f2bf(W2[idx]);
  } else if (b < 192) {
    int idx = (b - 128) * 256 + t;
    Wlb[idx] = f2bf(Wl[idx]);
  } else {
    int idx = (b - 192) * 256 + t;
    if (idx < N) count[idx] = 0;
  }
}

// ---------------------------------------------------------------------------
// histogram of destination indices (4 edges/thread, vectorized read)
// ---------------------------------------------------------------------------
__global__ void hist_kernel(const int* __restrict__ gi, int* __restrict__ count, int E) {
  int t = blockIdx.x * 256 + threadIdx.x;
  int base = t * 4;
  if (base + 3 < E) {
    int4 v = *(const int4*)(gi + base);
    atomicAdd(&count[v.x], 1);
    atomicAdd(&count[v.y], 1);
    atomicAdd(&count[v.z], 1);
    atomicAdd(&count[v.w], 1);
  } else {
    for (int k = base; k < E; ++k) atomicAdd(&count[gi[k]], 1);
  }
}

// ---------------------------------------------------------------------------
// exclusive scan of count -> start[0..N], woff (single block, 1024 threads,
// int4 phase-1 loads, 64 elems/thread)
// ---------------------------------------------------------------------------
__global__ __launch_bounds__(1024) void scan_kernel(const int* __restrict__ count,
                                                    int* __restrict__ start,
                                                    int* __restrict__ woff, int N) {
  __shared__ int wsum[16];
  const int tid = threadIdx.x, lane = tid & 63, wave = tid >> 6;
  int lo = tid * 64, hi = lo + 64; if (hi > N) hi = N;
  int s = 0;
  if (lo < N) {
    int k = lo;
    for (; k + 4 <= hi; k += 4) {
      int4 v = *(const int4*)(count + k);
      s += v.x + v.y + v.z + v.w;
    }
    for (; k < hi; ++k) s += count[k];
  }
  int v = s;
#pragma unroll
  for (int o = 1; o < 64; o <<= 1) {
    int u = __shfl_up(v, o, 64);
    if (lane >= o) v += u;
  }
  if (lane == 63) wsum[wave] = v;
  __syncthreads();
  if (wave == 0 && lane < 16) {
    int w = wsum[lane];
#pragma unroll
    for (int o = 1; o < 16; o <<= 1) {
      int u = __shfl_up(w, o, 64);
      if (lane >= o) w += u;
    }
    wsum[lane] = w;
  }
  __syncthreads();
  int base = (wave ? wsum[wave - 1] : 0) + (v - s);
  if (lo < N) {
    for (int i = lo; i < hi; ++i) {
      int c = count[i];
      start[i] = base; woff[i] = base; base += c;
    }
  }
  if (tid == 1023) start[N] = base;  // == E
}

// ---------------------------------------------------------------------------
// scatter: CSR by destination. edata[pos] = {e, j, i, 0} — single 16B store
// ---------------------------------------------------------------------------
__global__ void scatter_kernel(const int* __restrict__ gi, const int* __restrict__ gj,
                               int* __restrict__ woff, int4* __restrict__ edata, int E) {
  int e = blockIdx.x * 256 + threadIdx.x;
  if (e < E) {
    int i = gi[e];
    int pos = atomicAdd(&woff[i], 1);
    int4 ed; ed.x = e; ed.y = gj[e]; ed.z = i; ed.w = 0;
    edata[pos] = ed;
  }
}

// ---------------------------------------------------------------------------
// Wxh = x @ Wl^T + bl -> bf16   (bf16 MFMA, 64 rows/block)
// ---------------------------------------------------------------------------
__global__ __launch_bounds__(256, 2) void node_gemm_kernel(
    const float* __restrict__ x, const short* __restrict__ Wlb,
    const float* __restrict__ bl, short* __restrict__ WxhB, int N) {
  __shared__ short Wl_s[D * D];
  const int tid = threadIdx.x;
  const int lane = tid & 63, wave = tid >> 6;
  const int q = lane & 15, g = lane >> 4;

  for (int it = 0; it < 8; ++it) {
    int eoff = (it * 256 + tid) * 8;
    int row = eoff >> 7, col = eoff & 127;
    int scol = col ^ ((row & 7) << 3);
    *(short8_t*)&Wl_s[row * D + scol] = *(const short8_t*)&Wlb[eoff];
  }

  const int rbase = blockIdx.x * 64 + wave * 16;
  int arow = rbase + q; if (arow > N - 1) arow = N - 1;
  short8_t a[4];
  const float* src = x + (size_t)arow * D;
#pragma unroll
  for (int c = 0; c < 4; ++c) {
    int kb = c * 32 + g * 8;
    f32x4 v0 = *(const f32x4*)(src + kb);
    f32x4 v1 = *(const f32x4*)(src + kb + 4);
    short8_t t;
    t[0]=f2bf(v0.x); t[1]=f2bf(v0.y); t[2]=f2bf(v0.z); t[3]=f2bf(v0.w);
    t[4]=f2bf(v1.x); t[5]=f2bf(v1.y); t[6]=f2bf(v1.z); t[7]=f2bf(v1.w);
    a[c] = t;
  }

  __syncthreads();

  f32x4 acc[8];
#pragma unroll
  for (int n = 0; n < 8; ++n) acc[n] = f32x4{0.f, 0.f, 0.f, 0.f};
#pragma unroll
  for (int n = 0; n < 8; ++n) {
    int row = n * 16 + q;
    int sw = (row & 7) << 3;
#pragma unroll
    for (int c = 0; c < 4; ++c) {
      int col = (c * 32 + g * 8) ^ sw;
      short8_t b = *(const short8_t*)&Wl_s[row * D + col];
      acc[n] = __builtin_amdgcn_mfma_f32_16x16x32_bf16(a[c], b, acc[n], 0, 0, 0);
    }
  }

#pragma unroll
  for (int n = 0; n < 8; ++n) {
    int col = n * 16 + q;
    float bias = bl[col];
#pragma unroll
    for (int r = 0; r < 4; ++r) {
      int orow = rbase + g * 4 + r;
      if (orow < N) WxhB[(size_t)orow * D + col] = f2bf(acc[n][r] + bias);
    }
  }
}

// ---------------------------------------------------------------------------
// fused edge kernel (persistent, CSR order, 1-deep software pipeline):
//   m = (silu(rbf[e]@Wc^T + b0)) @ W2^T + b2 ; h[i] += segmented sum m ⊙ Wxh[j]
// prefetch of next tile's {edata, rbf, Wxh} overlaps current tile's GEMMs.
// ---------------------------------------------------------------------------
__global__ __launch_bounds__(256, 2) void fused_edge_kernel(
    const float* __restrict__ rbf, const float* __restrict__ b0v,
    const float* __restrict__ b2v, const short* __restrict__ Wcb,
    const short* __restrict__ W2b, const short* __restrict__ WxhB,
    const int4* __restrict__ edata, float* __restrict__ h, int E, int ntiles) {
  __shared__ short Wc_s[D * D];
  __shared__ short W2_s[D * D];
  __shared__ short m_s[4][16 * D];

  const int tid = threadIdx.x;
  const int lane = tid & 63, wave = tid >> 6;
  const int q = lane & 15, g = lane >> 4;

  for (int it = 0; it < 8; ++it) {
    int eoff = (it * 256 + tid) * 8;
    int row = eoff >> 7, col = eoff & 127;
    int scol = col ^ ((row & 7) << 3);
    *(short8_t*)&Wc_s[row * D + scol] = *(const short8_t*)&Wcb[eoff];
    *(short8_t*)&W2_s[row * D + scol] = *(const short8_t*)&W2b[eoff];
  }

  float b0r[8], b2r[8];
#pragma unroll
  for (int n = 0; n < 8; ++n) { b0r[n] = b0v[n * 16 + q]; b2r[n] = b2v[n * 16 + q]; }

  __syncthreads();

  short* ms = &m_s[wave][0];

  int tile = blockIdx.x;
  if (tile >= ntiles) return;

  // ---- prologue: load first tile's data into registers
  int eb = tile * 64 + wave * 16;
  int eq = eb + q; if (eq > E - 1) eq = E - 1;
  int4 ed = edata[eq];
  f32x4 rb[8];
  {
    const float* src = rbf + (size_t)ed.x * D;
#pragma unroll
    for (int c = 0; c < 4; ++c) {
      rb[c * 2]     = *(const f32x4*)(src + c * 32 + g * 8);
      rb[c * 2 + 1] = *(const f32x4*)(src + c * 32 + g * 8 + 4);
    }
  }
  unsigned wv[16];
#pragma unroll
  for (int r = 0; r < 16; ++r) {
    int jr = __shfl(ed.y, r, 64);
    wv[r] = *(const unsigned*)&WxhB[(size_t)jr * D + lane * 2];
  }

  while (true) {
    const int ntile = tile + gridDim.x;
    const bool hnext = ntile < ntiles;
    const int ptile = hnext ? ntile : tile;  // clamp: last iter re-prefetches self

    // convert current rbf -> A fragments
    short8_t a[4];
#pragma unroll
    for (int c = 0; c < 4; ++c) {
      f32x4 v0 = rb[c * 2], v1 = rb[c * 2 + 1];
      short8_t t;
      t[0]=f2bf(v0.x); t[1]=f2bf(v0.y); t[2]=f2bf(v0.z); t[3]=f2bf(v0.w);
      t[4]=f2bf(v1.x); t[5]=f2bf(v1.y); t[6]=f2bf(v1.z); t[7]=f2bf(v1.w);
      a[c] = t;
    }

    // issue next tile's index load (16B) — hides under GEMM1
    const int neb = ptile * 64 + wave * 16;
    int neq = neb + q; if (neq > E - 1) neq = E - 1;
    int4 ed2 = edata[neq];

    // GEMM1: u = rbf @ Wc^T
    f32x4 acc[8];
#pragma unroll
    for (int n = 0; n < 8; ++n) acc[n] = f32x4{0.f, 0.f, 0.f, 0.f};
#pragma unroll
    for (int n = 0; n < 8; ++n) {
      int row = n * 16 + q;
      int sw = (row & 7) << 3;
#pragma unroll
      for (int c = 0; c < 4; ++c) {
        int col = (c * 32 + g * 8) ^ sw;
        short8_t b = *(const short8_t*)&Wc_s[row * D + col];
        acc[n] = __builtin_amdgcn_mfma_f32_16x16x32_bf16(a[c], b, acc[n], 0, 0, 0);
      }
    }

    // silu(u + b0) -> wave-private LDS tile (bf16, swizzled)
#pragma unroll
    for (int n = 0; n < 8; ++n) {
      int col = n * 16 + q;
#pragma unroll
      for (int r = 0; r < 4; ++r) {
        int row = g * 4 + r;
        float u = acc[n][r] + b0r[n];
        float s = u / (1.0f + __expf(-u));
        ms[row * D + (col ^ ((row & 7) << 3))] = f2bf(s);
      }
    }

    // issue next tile's rbf gather — hides under GEMM2 + reduce
    f32x4 rb2[8];
    {
      const float* src2 = rbf + (size_t)ed2.x * D;
#pragma unroll
      for (int c = 0; c < 4; ++c) {
        rb2[c * 2]     = *(const f32x4*)(src2 + c * 32 + g * 8);
        rb2[c * 2 + 1] = *(const f32x4*)(src2 + c * 32 + g * 8 + 4);
      }
    }

    // read transposed A fragments for GEMM2
    short8_t a2[4];
    {
      int sw = (q & 7) << 3;
#pragma unroll
      for (int c = 0; c < 4; ++c) {
        int col = (c * 32 + g * 8) ^ sw;
        a2[c] = *(const short8_t*)&ms[q * D + col];
      }
    }

    // GEMM2: m = silu(u) @ W2^T
    f32x4 acc2[8];
#pragma unroll
    for (int n = 0; n < 8; ++n) acc2[n] = f32x4{0.f, 0.f, 0.f, 0.f};
#pragma unroll
    for (int n = 0; n < 8; ++n) {
      int row = n * 16 + q;
      int sw = (row & 7) << 3;
#pragma unroll
      for (int c = 0; c < 4; ++c) {
        int col = (c * 32 + g * 8) ^ sw;
        short8_t b = *(const short8_t*)&W2_s[row * D + col];
        acc2[n] = __builtin_amdgcn_mfma_f32_16x16x32_bf16(a2[c], b, acc2[n], 0, 0, 0);
      }
    }

    // m + b2 -> bf16 back into the wave tile
#pragma unroll
    for (int n = 0; n < 8; ++n) {
      int col = n * 16 + q;
#pragma unroll
      for (int r = 0; r < 4; ++r) {
        int row = g * 4 + r;
        ms[row * D + (col ^ ((row & 7) << 3))] = f2bf(acc2[n][r] + b2r[n]);
      }
    }

    // issue next tile's Wxh gather — hides under the reduce + next GEMM1
    unsigned wv2[16];
#pragma unroll
    for (int r = 0; r < 16; ++r) {
      int jr = __shfl(ed2.y, r, 64);
      wv2[r] = *(const unsigned*)&WxhB[(size_t)jr * D + lane * 2];
    }

    // segmented reduce: lane owns cols {2*lane, 2*lane+1}; rows sorted by i
    int nv = E - eb; if (nv > 16) nv = 16;
    float a0 = 0.f, a1 = 0.f;
    int cur = -1;
#pragma unroll
    for (int r = 0; r < 16; ++r) {
      if (r < nv) {
        int ir = __shfl(ed.z, r, 64);
        if (ir != cur) {
          if (cur >= 0) {
            float* dst = &h[(size_t)cur * D + lane * 2];
            __hip_atomic_fetch_add(dst, a0, __ATOMIC_RELAXED, __HIP_MEMORY_SCOPE_AGENT);
            __hip_atomic_fetch_add(dst + 1, a1, __ATOMIC_RELAXED, __HIP_MEMORY_SCOPE_AGENT);
            a0 = a1 = 0.f;
          }
          cur = ir;
        }
        unsigned mv = *(const unsigned*)&ms[r * D + ((lane * 2) ^ ((r & 7) << 3))];
        a0 += bf2f(mv & 0xffffu) * bf2f(wv[r] & 0xffffu);
        a1 += bf2f(mv >> 16) * bf2f(wv[r] >> 16);
      }
    }
    if (cur >= 0) {
      float* dst = &h[(size_t)cur * D + lane * 2];
      __hip_atomic_fetch_add(dst, a0, __ATOMIC_RELAXED, __HIP_MEMORY_SCOPE_AGENT);
      __hip_atomic_fetch_add(dst + 1, a1, __ATOMIC_RELAXED, __HIP_MEMORY_SCOPE_AGENT);
    }

    if (!hnext) break;
    tile = ntile; eb = neb; ed = ed2;
#pragma unroll
    for (int u = 0; u < 8; ++u) rb[u] = rb2[u];
#pragma unroll
    for (int r = 0; r < 16; ++r) wv[r] = wv2[r];
  }
}

// ---------------------------------------------------------------------------
// LayerNorm over h = x + agg : one wave per row
// ---------------------------------------------------------------------------
__global__ __launch_bounds__(256) void ln_kernel(const float* __restrict__ agg,
                                                 const float* __restrict__ x,
                                                 const float* __restrict__ gamma,
                                                 const float* __restrict__ beta,
                                                 float* __restrict__ out, int N) {
  int wave = threadIdx.x >> 6, lane = threadIdx.x & 63;
  long row = (long)blockIdx.x * 4 + wave;
  if (row >= N) return;
  int c = lane * 2;
  f32x2 av = *(const f32x2*)&agg[row * D + c];
  f32x2 xv = *(const f32x2*)&x[row * D + c];
  float h0 = av.x + xv.x, h1 = av.y + xv.y;
  float sum = h0 + h1;
  float sq = h0 * h0 + h1 * h1;
#pragma unroll
  for (int o = 32; o; o >>= 1) {
    sum += __shfl_xor(sum, o, 64);
    sq += __shfl_xor(sq, o, 64);
  }
  float mu = sum * (1.0f / 128.0f);
  float var = sq * (1.0f / 128.0f) - mu * mu;
  float rstd = rsqrtf(var + 1e-5f);
  f32x2 gv = *(const f32x2*)&gamma[c];
  f32x2 bv = *(const f32x2*)&beta[c];
  f32x2 ov;
  ov.x = (h0 - mu) * rstd * gv.x + bv.x;
  ov.y = (h1 - mu) * rstd * gv.y + bv.y;
  *(f32x2*)&out[row * D + c] = ov;
}

// ---------------------------------------------------------------------------
extern "C" void kernel_launch(void* const* d_in, const int* in_sizes, int n_in,
                              void* d_out, int out_size, void* d_ws, size_t ws_size,
                              hipStream_t stream) {
  const float* x    = (const float*)d_in[0];
  const int*   gi   = (const int*)d_in[1];
  const int*   gj   = (const int*)d_in[2];
  const float* rbf  = (const float*)d_in[3];
  const float* Wl   = (const float*)d_in[4];
  const float* bl   = (const float*)d_in[5];
  const float* W0   = (const float*)d_in[6];
  const float* b0   = (const float*)d_in[7];
  const float* W2   = (const float*)d_in[8];
  const float* b2   = (const float*)d_in[9];
  const float* gam  = (const float*)d_in[10];
  const float* bet  = (const float*)d_in[11];

  const int N = in_sizes[0] / D;  // 50000
  const int E = in_sizes[1];      // 600000

  char* ws = (char*)d_ws;
  size_t off = 0;
  float* h    = (float*)(ws + off); off += (size_t)N * D * 4;   // agg (zeroed)
  short* WxhB = (short*)(ws + off); off += (size_t)N * D * 2;
  int4*  edat = (int4*)(ws + off);  off += (size_t)E * 16;      // 16B-aligned
  int*   cnt  = (int*)(ws + off);   off += (size_t)N * 4;
  int*   strt = (int*)(ws + off);   off += (size_t)(N + 1) * 4;
  int*   woff = (int*)(ws + off);   off += (size_t)N * 4;
  short* Wcb  = (short*)(ws + off); off += D * D * 2;
  short* W2b  = (short*)(ws + off); off += D * D * 2;
  short* Wlb  = (short*)(ws + off); off += D * D * 2;

  const int ntiles = (E + 63) / 64;

  hipMemsetAsync(h, 0, (size_t)N * D * 4, stream);
  prep_kernel<<<192 + (N + 255) / 256, 256, 0, stream>>>(W0, W2, Wl, Wcb, W2b, Wlb, cnt, N);
  hist_kernel<<<(E / 4 + 255) / 256, 256, 0, stream>>>(gi, cnt, E);
  scan_kernel<<<1, 1024, 0, stream>>>(cnt, strt, woff, N);
  scatter_kernel<<<(E + 255) / 256, 256, 0, stream>>>(gi, gj, woff, edat, E);
  node_gemm_kernel<<<(N + 63) / 64, 256, 0, stream>>>(x, Wlb, bl, WxhB, N);
  fused_edge_kernel<<<512, 256, 0, stream>>>(rbf, b0, b2, Wcb, W2b, WxhB,
                                             edat, h, E, ntiles);
  ln_kernel<<<(N + 3) / 4, 256, 0, stream>>>(h, x, gam, bet, (float*)d_out, N);
}